// Round 3
// baseline (124.279 us; speedup 1.0000x reference)
//
#include <hip/hip_runtime.h>
#include <hip/hip_bf16.h>
#include <math.h>

#define NQ 1024
#define BS 16
#define NC 256
#define NPRED (BS*NQ)   // 16384 pred boxes
#define MT 1024         // targets
#define GEPS 1e-6f

__device__ __forceinline__ float rcp_fast(float x) { return __builtin_amdgcn_rcpf(x); }
__device__ __forceinline__ float rfl(float x) {
    return __int_as_float(__builtin_amdgcn_readfirstlane(__float_as_int(x)));
}

// ---------------- Kernel 1: preprocess (extents only) ----------------
// 68 blocks x 256: one box per thread; preds then tgts.
//   preds -> pext[n*8]  = {mn0,mn1,mn2,mx0, mx1,mx2,vol,pad}
//   tgts  -> trec[m*16] = {mn0,mn1,mn2,mx0, mx1,mx2,vol,label_bits, b0..b3, b4,b5,pad,pad}
__global__ __launch_bounds__(256) void prep_kernel(
    const float* __restrict__ pcorners,   // [NPRED, 8, 3]
    const float* __restrict__ tcorners,   // [MT, 8, 3]
    const int*   __restrict__ tlabels,    // [MT]
    const float* __restrict__ tboxes,     // [MT, 6]
    float* __restrict__ pext,             // [NPRED, 8]
    float* __restrict__ trec)             // [MT, 16]
{
    int b = blockIdx.x*256 + threadIdx.x;
    bool is_pred = (b < NPRED);
    if (b >= NPRED + MT) return;
    int idx = is_pred ? b : (b - NPRED);
    const float* src = is_pred ? pcorners : tcorners;
    float buf[24];
    const float4* s4 = (const float4*)(src + (size_t)idx*24);
    #pragma unroll
    for (int i = 0; i < 6; ++i) *(float4*)&buf[i*4] = s4[i];
    float mn0 = buf[0], mn1 = buf[1], mn2 = buf[2];
    float mx0 = mn0, mx1 = mn1, mx2 = mn2;
    #pragma unroll
    for (int c = 1; c < 8; ++c) {
        mn0 = fminf(mn0, buf[c*3+0]); mx0 = fmaxf(mx0, buf[c*3+0]);
        mn1 = fminf(mn1, buf[c*3+1]); mx1 = fmaxf(mx1, buf[c*3+1]);
        mn2 = fminf(mn2, buf[c*3+2]); mx2 = fmaxf(mx2, buf[c*3+2]);
    }
    float vol = (mx0-mn0)*(mx1-mn1)*(mx2-mn2);
    if (is_pred) {
        *(float4*)(pext + (size_t)idx*8)     = make_float4(mn0, mn1, mn2, mx0);
        *(float4*)(pext + (size_t)idx*8 + 4) = make_float4(mx1, mx2, vol, 0.0f);
    } else {
        float2 b0 = *(const float2*)(tboxes + (size_t)idx*6);
        float2 b1 = *(const float2*)(tboxes + (size_t)idx*6 + 2);
        float2 b2 = *(const float2*)(tboxes + (size_t)idx*6 + 4);
        float lbf = __int_as_float(tlabels[idx]);
        float* d = trec + (size_t)idx*16;
        *(float4*)(d)      = make_float4(mn0, mn1, mn2, mx0);
        *(float4*)(d + 4)  = make_float4(mx1, mx2, vol, lbf);
        *(float4*)(d + 8)  = make_float4(b0.x, b0.y, b1.x, b1.y);
        *(float4*)(d + 12) = make_float4(b2.x, b2.y, 0.0f, 0.0f);
    }
}

// ---------------- Kernel 2: fused softmax + pairwise cost ----------------
// block = 16 n-rows x 512 m-cols; grid 2048 = 8 blocks/CU x 4 waves = 32 waves/CU.
// Softmax offsets computed in-block (wave reduce). Wave w owns rows w*4..w*4+3
// (pred data -> SGPRs via readfirstlane). Each lane: 2 adjacent m per chunk,
// 4 chunks of 128 m; float2 output stores.
__global__ __launch_bounds__(256) void cost_kernel(
    const float* __restrict__ logits,   // [NPRED, NC]
    const float* __restrict__ pboxes,   // [NPRED, 6]
    const float* __restrict__ pext,     // [NPRED, 8]
    const float* __restrict__ trec,     // [MT, 16]
    float* __restrict__ out)            // [NPRED, MT]
{
    __shared__ float sProb[16][NC];
    __shared__ float sOff[16];
    const int t = threadIdx.x;
    const int lane = t & 63;
    const int wave = t >> 6;
    const int nt = blockIdx.x >> 1;
    const int mt = blockIdx.x & 1;
    const int n_base = nt * 16;
    const int m_base = mt * 512;

    // Issue pred loads early (independent of LDS phases)
    float4 pa[4], pb[4];
    float2 pc0[4], pc1[4], pc2[4];
    #pragma unroll
    for (int i = 0; i < 4; ++i) {
        const int n = n_base + wave*4 + i;
        pa[i]  = *(const float4*)(pext + (size_t)n*8);
        pb[i]  = *(const float4*)(pext + (size_t)n*8 + 4);
        pc0[i] = *(const float2*)(pboxes + (size_t)n*6);
        pc1[i] = *(const float2*)(pboxes + (size_t)n*6 + 2);
        pc2[i] = *(const float2*)(pboxes + (size_t)n*6 + 4);
    }

    // Phase 1: raw logits -> LDS
    #pragma unroll
    for (int r = 0; r < 16; ++r)
        sProb[r][t] = logits[(size_t)(n_base + r)*NC + t];
    __syncthreads();

    // Phase 2: per-row softmax offset off = max + ln(sum exp(l - max)); wave w does rows 4w..4w+3
    #pragma unroll
    for (int i = 0; i < 4; ++i) {
        const int r = wave*4 + i;
        float x0 = sProb[r][lane], x1 = sProb[r][lane+64],
              x2 = sProb[r][lane+128], x3 = sProb[r][lane+192];
        float mx = fmaxf(fmaxf(x0,x1), fmaxf(x2,x3));
        #pragma unroll
        for (int s = 1; s < 64; s <<= 1) mx = fmaxf(mx, __shfl_xor(mx, s));
        float se = __expf(x0-mx) + __expf(x1-mx) + __expf(x2-mx) + __expf(x3-mx);
        #pragma unroll
        for (int s = 1; s < 64; s <<= 1) se += __shfl_xor(se, s);
        if (lane == 0) sOff[r] = mx + __logf(se);
    }

    // SGPR-ize wave-uniform pred data
    float smn[4][3], smx[4][3], spe[4][3], svol[4], spb[4][6];
    #pragma unroll
    for (int i = 0; i < 4; ++i) {
        smn[i][0]=rfl(pa[i].x);  smn[i][1]=rfl(pa[i].y);  smn[i][2]=rfl(pa[i].z);
        smx[i][0]=rfl(pa[i].w);  smx[i][1]=rfl(pb[i].x);  smx[i][2]=rfl(pb[i].y);
        svol[i]=rfl(pb[i].z);
        spe[i][0]=rfl(pa[i].w-pa[i].x); spe[i][1]=rfl(pb[i].x-pa[i].y); spe[i][2]=rfl(pb[i].y-pa[i].z);
        spb[i][0]=rfl(pc0[i].x); spb[i][1]=rfl(pc0[i].y); spb[i][2]=rfl(pc1[i].x);
        spb[i][3]=rfl(pc1[i].y); spb[i][4]=rfl(pc2[i].x); spb[i][5]=rfl(pc2[i].y);
    }
    __syncthreads();

    // Phase 3: rewrite LDS with probs
    #pragma unroll
    for (int r = 0; r < 16; ++r)
        sProb[r][t] = __expf(sProb[r][t] - sOff[r]);
    __syncthreads();

    const size_t out_row0 = (size_t)(n_base + wave*4) * MT;

    #pragma unroll 1
    for (int c = 0; c < 4; ++c) {
        const int m0 = m_base + c*128 + lane*2;
        const float* tr = trec + (size_t)m0*16;
        float4 A0 = *(const float4*)(tr);      float4 B0 = *(const float4*)(tr + 4);
        float4 C0 = *(const float4*)(tr + 8);  float2 D0 = *(const float2*)(tr + 12);
        float4 A1 = *(const float4*)(tr + 16); float4 B1 = *(const float4*)(tr + 20);
        float4 C1 = *(const float4*)(tr + 24); float2 D1 = *(const float2*)(tr + 28);

        const int lb0 = __float_as_int(B0.w);
        const int lb1 = __float_as_int(B1.w);
        float prv0[4], prv1[4];
        #pragma unroll
        for (int i = 0; i < 4; ++i) {
            prv0[i] = sProb[wave*4+i][lb0];
            prv1[i] = sProb[wave*4+i][lb1];
        }

        // target extents (reused across 4 rows)
        const float te00 = A0.w - A0.x, te01 = B0.x - A0.y, te02 = B0.y - A0.z;
        const float te10 = A1.w - A1.x, te11 = B1.x - A1.y, te12 = B1.y - A1.z;

        #pragma unroll
        for (int i = 0; i < 4; ++i) {
            // ---- m0 (j=0) ----
            float dr0 = fminf(smx[i][0],A0.w) - fmaxf(smn[i][0],A0.x);
            float dr1 = fminf(smx[i][1],B0.x) - fmaxf(smn[i][1],A0.y);
            float dr2 = fminf(smx[i][2],B0.y) - fmaxf(smn[i][2],A0.z);
            float inter0 = fmaxf(dr0,0.f)*fmaxf(dr1,0.f)*fmaxf(dr2,0.f);
            float enc0 = (spe[i][0]+(te00-dr0))*(spe[i][1]+(te01-dr1))*(spe[i][2]+(te02-dr2));
            float uni0 = svol[i] + B0.z - inter0;
            float giou0 = inter0*rcp_fast(uni0+GEPS) - (enc0-uni0)*rcp_fast(enc0+GEPS);
            float l10 = fabsf(spb[i][0]-C0.x) + fabsf(spb[i][1]-C0.y) + fabsf(spb[i][2]-C0.z)
                      + fabsf(spb[i][3]-C0.w) + fabsf(spb[i][4]-D0.x) + fabsf(spb[i][5]-D0.y);
            float r0 = l10 - prv0[i] - giou0;
            // ---- m0+1 (j=1) ----
            float er0 = fminf(smx[i][0],A1.w) - fmaxf(smn[i][0],A1.x);
            float er1 = fminf(smx[i][1],B1.x) - fmaxf(smn[i][1],A1.y);
            float er2 = fminf(smx[i][2],B1.y) - fmaxf(smn[i][2],A1.z);
            float inter1 = fmaxf(er0,0.f)*fmaxf(er1,0.f)*fmaxf(er2,0.f);
            float enc1 = (spe[i][0]+(te10-er0))*(spe[i][1]+(te11-er1))*(spe[i][2]+(te12-er2));
            float uni1 = svol[i] + B1.z - inter1;
            float giou1 = inter1*rcp_fast(uni1+GEPS) - (enc1-uni1)*rcp_fast(enc1+GEPS);
            float l11 = fabsf(spb[i][0]-C1.x) + fabsf(spb[i][1]-C1.y) + fabsf(spb[i][2]-C1.z)
                      + fabsf(spb[i][3]-C1.w) + fabsf(spb[i][4]-D1.x) + fabsf(spb[i][5]-D1.y);
            float r1 = l11 - prv1[i] - giou1;

            *(float2*)(out + out_row0 + (size_t)i*MT + m0) = make_float2(r0, r1);
        }
    }
}

extern "C" void kernel_launch(void* const* d_in, const int* in_sizes, int n_in,
                              void* d_out, int out_size, void* d_ws, size_t ws_size,
                              hipStream_t stream) {
    const float* logits   = (const float*)d_in[0];  // [16,1024,256]
    const float* pboxes   = (const float*)d_in[1];  // [16,1024,6]
    const float* pcorners = (const float*)d_in[2];  // [16,1024,8,3]
    const int*   tlabels  = (const int*)d_in[3];    // [1024]
    const float* tboxes   = (const float*)d_in[4];  // [1024,6]
    const float* tcorners = (const float*)d_in[5];  // [1024,8,3]
    float* out = (float*)d_out;

    float* ws = (float*)d_ws;
    float* pext = ws;                  // 16384*8 = 131072 floats
    float* trec = ws + 131072;         // 1024*16 = 16384 floats
    // total ws use: 589,824 bytes (ws is 256 MiB per harness poison fills)

    prep_kernel<<<(NPRED + MT + 255)/256, 256, 0, stream>>>(pcorners, tcorners,
                                                            tlabels, tboxes, pext, trec);
    cost_kernel<<<2048, 256, 0, stream>>>(logits, pboxes, pext, trec, out);
}

// Round 4
// 116.074 us; speedup vs baseline: 1.0707x; 1.0707x over previous
//
#include <hip/hip_runtime.h>
#include <hip/hip_bf16.h>
#include <math.h>

#define NQ 1024
#define BS 16
#define NC 256
#define NPRED (BS*NQ)   // 16384 pred boxes
#define MT 1024         // targets
#define GEPS 1e-6f
#define ROWS 16         // n-rows per block in cost_kernel

__device__ __forceinline__ float rcp_fast(float x) { return __builtin_amdgcn_rcpf(x); }
__device__ __forceinline__ float rfl(float x) {
    return __int_as_float(__builtin_amdgcn_readfirstlane(__float_as_int(x)));
}

// ---------------- Kernel 1: preprocess ----------------
// blocks [0, 4096): softmax row offset (4 rows/block, one wave per row)
//   rowoff[row] = rowmax + ln(sum exp(l - rowmax));  prob = exp(l - rowoff)
// blocks [4096, 4164): box extents
//   preds -> pext[n*8]  = {mn0,mn1,mn2,mx0, mx1,mx2,vol,pad}
//   tgts  -> trec[m*16] = {mn0,mn1,mn2,mx0, mx1,mx2,vol,label_bits, b0..b3, b4,b5,pad,pad}
__global__ __launch_bounds__(256) void prep_kernel(
    const float* __restrict__ logits,     // [NPRED, NC]
    const float* __restrict__ pcorners,   // [NPRED, 8, 3]
    const float* __restrict__ tcorners,   // [MT, 8, 3]
    const int*   __restrict__ tlabels,    // [MT]
    const float* __restrict__ tboxes,     // [MT, 6]
    float* __restrict__ rowoff,           // [NPRED]
    float* __restrict__ pext,             // [NPRED, 8]
    float* __restrict__ trec)             // [MT, 16]
{
    int t = threadIdx.x;
    int blk = blockIdx.x;
    if (blk < NPRED/4) {
        int wave = t >> 6, lane = t & 63;
        int row = blk*4 + wave;
        const float4 v = *(const float4*)(logits + (size_t)row*NC + lane*4);
        float mx = fmaxf(fmaxf(v.x, v.y), fmaxf(v.z, v.w));
        #pragma unroll
        for (int s = 1; s < 64; s <<= 1) mx = fmaxf(mx, __shfl_xor(mx, s));
        float e = __expf(v.x - mx) + __expf(v.y - mx) + __expf(v.z - mx) + __expf(v.w - mx);
        #pragma unroll
        for (int s = 1; s < 64; s <<= 1) e += __shfl_xor(e, s);
        if (lane == 0) rowoff[row] = mx + __logf(e);
    } else {
        int b = (blk - NPRED/4)*256 + t;
        bool is_pred = (b < NPRED);
        if (b >= NPRED + MT) return;
        int idx = is_pred ? b : (b - NPRED);
        const float* src = is_pred ? pcorners : tcorners;
        float buf[24];
        const float4* s4 = (const float4*)(src + (size_t)idx*24);
        #pragma unroll
        for (int i = 0; i < 6; ++i) *(float4*)&buf[i*4] = s4[i];
        float mn0 = buf[0], mn1 = buf[1], mn2 = buf[2];
        float mx0 = mn0, mx1 = mn1, mx2 = mn2;
        #pragma unroll
        for (int c = 1; c < 8; ++c) {
            mn0 = fminf(mn0, buf[c*3+0]); mx0 = fmaxf(mx0, buf[c*3+0]);
            mn1 = fminf(mn1, buf[c*3+1]); mx1 = fmaxf(mx1, buf[c*3+1]);
            mn2 = fminf(mn2, buf[c*3+2]); mx2 = fmaxf(mx2, buf[c*3+2]);
        }
        float vol = (mx0-mn0)*(mx1-mn1)*(mx2-mn2);
        if (is_pred) {
            *(float4*)(pext + (size_t)idx*8)     = make_float4(mn0, mn1, mn2, mx0);
            *(float4*)(pext + (size_t)idx*8 + 4) = make_float4(mx1, mx2, vol, 0.0f);
        } else {
            float2 b0 = *(const float2*)(tboxes + (size_t)idx*6);
            float2 b1 = *(const float2*)(tboxes + (size_t)idx*6 + 2);
            float2 b2 = *(const float2*)(tboxes + (size_t)idx*6 + 4);
            float lbf = __int_as_float(tlabels[idx]);
            float* d = trec + (size_t)idx*16;
            *(float4*)(d)      = make_float4(mn0, mn1, mn2, mx0);
            *(float4*)(d + 4)  = make_float4(mx1, mx2, vol, lbf);
            *(float4*)(d + 8)  = make_float4(b0.x, b0.y, b1.x, b1.y);
            *(float4*)(d + 12) = make_float4(b2.x, b2.y, 0.0f, 0.0f);
        }
    }
}

// ---------------- Kernel 2: pairwise cost ----------------
// block = 16 n-rows x 256 m-cols; grid 4096 (1024 n-tiles x 4 m-tiles).
// Each LANE owns one m for the whole block: target record loaded ONCE (4 vector
// loads, 14 regs), reused across all 16 rows. Per-row pred data is block-uniform
// -> readfirstlane to SGPRs. One barrier; 16 independent rows of ILP per thread.
__global__ __launch_bounds__(256) void cost_kernel(
    const float* __restrict__ logits,   // [NPRED, NC]
    const float* __restrict__ pboxes,   // [NPRED, 6]
    const float* __restrict__ rowoff,   // [NPRED]
    const float* __restrict__ pext,     // [NPRED, 8]
    const float* __restrict__ trec,     // [MT, 16]
    float* __restrict__ out)            // [NPRED, MT]
{
    __shared__ float sProb[ROWS][NC + 1];   // stride 257: gather rotates banks per row
    const int t = threadIdx.x;
    const int nt = blockIdx.x >> 2;
    const int mt = blockIdx.x & 3;
    const int n_base = nt * ROWS;
    const int m = mt * 256 + t;

    // Lane's target record (issued before LDS fill; reused for all 16 rows)
    const float* tr = trec + (size_t)m*16;
    const float4 A = *(const float4*)(tr);
    const float4 B = *(const float4*)(tr + 4);
    const float4 C = *(const float4*)(tr + 8);
    const float2 D = *(const float2*)(tr + 12);

    // Prob tile: sProb[r][c] = exp(logits[row][c] - rowoff[row])
    #pragma unroll
    for (int r = 0; r < ROWS; ++r) {
        const int row = n_base + r;
        sProb[r][t] = __expf(logits[(size_t)row*NC + t] - rowoff[row]);
    }

    const float tmn0=A.x, tmn1=A.y, tmn2=A.z, tmx0=A.w;
    const float tmx1=B.x, tmx2=B.y, vt=B.z;
    const int   lb = __float_as_int(B.w);
    const float te0 = tmx0-tmn0, te1 = tmx1-tmn1, te2 = tmx2-tmn2;
    __syncthreads();

    #pragma unroll 4
    for (int r = 0; r < ROWS; ++r) {
        const int n = n_base + r;
        // block-uniform pred data -> SGPRs
        const float4 pa = *(const float4*)(pext + (size_t)n*8);
        const float4 pb = *(const float4*)(pext + (size_t)n*8 + 4);
        const float2 c0 = *(const float2*)(pboxes + (size_t)n*6);
        const float2 c1 = *(const float2*)(pboxes + (size_t)n*6 + 2);
        const float2 c2 = *(const float2*)(pboxes + (size_t)n*6 + 4);
        const float pmn0=rfl(pa.x), pmn1=rfl(pa.y), pmn2=rfl(pa.z);
        const float pmx0=rfl(pa.w), pmx1=rfl(pb.x), pmx2=rfl(pb.y);
        const float vp=rfl(pb.z);
        const float pe0=rfl(pa.w-pa.x), pe1=rfl(pb.x-pa.y), pe2=rfl(pb.y-pa.z);
        const float q0=rfl(c0.x), q1=rfl(c0.y), q2=rfl(c1.x);
        const float q3=rfl(c1.y), q4=rfl(c2.x), q5=rfl(c2.y);

        const float prob = sProb[r][lb];

        float d0 = fminf(pmx0,tmx0) - fmaxf(pmn0,tmn0);
        float d1 = fminf(pmx1,tmx1) - fmaxf(pmn1,tmn1);
        float d2 = fminf(pmx2,tmx2) - fmaxf(pmn2,tmn2);
        float inter = fmaxf(d0,0.f)*fmaxf(d1,0.f)*fmaxf(d2,0.f);
        float enc = (pe0+(te0-d0))*(pe1+(te1-d1))*(pe2+(te2-d2));  // min+max = sum identity
        float uni = vp + vt - inter;
        float giou = inter*rcp_fast(uni+GEPS) - (enc-uni)*rcp_fast(enc+GEPS);
        float l1 = fabsf(q0-C.x) + fabsf(q1-C.y) + fabsf(q2-C.z)
                 + fabsf(q3-C.w) + fabsf(q4-D.x) + fabsf(q5-D.y);
        out[(size_t)n*MT + m] = l1 - prob - giou;
    }
}

extern "C" void kernel_launch(void* const* d_in, const int* in_sizes, int n_in,
                              void* d_out, int out_size, void* d_ws, size_t ws_size,
                              hipStream_t stream) {
    const float* logits   = (const float*)d_in[0];  // [16,1024,256]
    const float* pboxes   = (const float*)d_in[1];  // [16,1024,6]
    const float* pcorners = (const float*)d_in[2];  // [16,1024,8,3]
    const int*   tlabels  = (const int*)d_in[3];    // [1024]
    const float* tboxes   = (const float*)d_in[4];  // [1024,6]
    const float* tcorners = (const float*)d_in[5];  // [1024,8,3]
    float* out = (float*)d_out;

    float* ws = (float*)d_ws;
    float* rowoff = ws;                        // 16384 floats
    float* pext   = ws + 16384;                // 16384*8 = 131072 floats
    float* trec   = ws + 16384 + 131072;       // 1024*16 = 16384 floats
    // total ws use: 655,360 bytes

    int prep_blocks = NPRED/4 + (NPRED + MT + 255)/256;   // 4096 + 68
    prep_kernel<<<prep_blocks, 256, 0, stream>>>(logits, pcorners, tcorners,
                                                 tlabels, tboxes, rowoff, pext, trec);
    cost_kernel<<<4096, 256, 0, stream>>>(logits, pboxes, rowoff, pext, trec, out);
}